// Round 3
// baseline (68.107 us; speedup 1.0000x reference)
//
#include <hip/hip_runtime.h>
#include <hip/hip_bf16.h>
#include <math.h>

// Problem constants (B,U,D) = (4096, 256, 128)
#define BN 4096
#define UN 256
#define DN 128
#define MROW 16        // batch rows per block (one M=16 MFMA tile)
#define BLOCK 1024     // 16 waves: wave w owns u-tile w
#define LSTRIDE 260    // logits row stride; 260 % 32 == 4 -> 2-way banks (free)

typedef __attribute__((ext_vector_type(8))) short short8x;   // 8 bf16
typedef __attribute__((ext_vector_type(4))) float float4x;   // MFMA C/D

__device__ inline uint pack2bf(float a, float b) {
    __hip_bfloat16 ha = __float2bfloat16(a);
    __hip_bfloat16 hb = __float2bfloat16(b);
    return (uint)(*(ushort*)&ha) | ((uint)(*(ushort*)&hb) << 16);
}

// Single fused kernel, register-pressure-controlled.
// 1024-thread block => 16 waves/CU => hard cap 128 VGPR/lane. Round-1 staged
// all 16 float4 of W/bias operands (64 VGPRs) before packing and flirted with
// the spill cliff. Here the f32->bf16 pack streams per K-chunk with a depth-1
// pipeline: live operand set = cur(4 float4) + next(4 float4) = 32 VGPRs.
__global__ __launch_bounds__(BLOCK) void fused_kernel(
    const float* __restrict__ x, const float* __restrict__ W,
    const float* __restrict__ bias, float* __restrict__ out)
{
    __shared__ __align__(16) uint XL[MROW * DN / 2];   // 4 KB, bf16 fragment order
    __shared__ float nv2_lds[MROW];
    __shared__ float logits[MROW][LSTRIDE];            // ~16.6 KB

    const int t    = threadIdx.x;
    const int lane = t & 63;
    const int wave = t >> 6;          // u-tile index; also x-row during staging
    const int m16  = lane & 15;
    const int q    = lane >> 4;
    const int b0   = blockIdx.x * MROW;
    const int u    = wave * 16 + m16;

    // ---- critical-path load first: this wave's x row (feeds the barrier)
    const int d0x = lane * 2;
    const float2 xv = *(const float2*)(x + (size_t)(b0 + wave) * DN + d0x);

    // ---- pipeline prologue: ks=0 W/bias operands (4x dwordx4)
    const float4* Wrow = (const float4*)(W    + (size_t)u * DN);
    const float4* Brow = (const float4*)(bias + (size_t)u * DN);
    const int cbase = q * 2;                 // float4 index of (q*8)/4
    float4 cw0 = Wrow[cbase], cw1 = Wrow[cbase + 1];
    float4 cb0 = Brow[cbase], cb1 = Brow[cbase + 1];

    // ---- stage x tile into LDS (bf16 fragment order) + exact f32 ||x||^2
    {
        float sq = fmaf(xv.x, xv.x, xv.y * xv.y);
        #pragma unroll
        for (int off = 32; off; off >>= 1) sq += __shfl_xor(sq, off);
        if (lane == 0) nv2_lds[wave] = sq;
        const int ks = d0x >> 5, qq = (d0x & 31) >> 3;
        XL[(ks * 64 + qq * 16 + wave) * 4 + ((d0x & 7) >> 1)] = pack2bf(xv.x, xv.y);
    }

    // ---- streamed in-register prep: bf16 B-fragments + per-u scalar partials
    float nb2 = 0.f, bw = 0.f, wn2 = 0.f;
    short8x wf[4], bf[4];
    #pragma unroll
    for (int ks = 0; ks < 4; ++ks) {
        float4 nw0, nw1, nb0v, nb1v;
        if (ks < 3) {                         // depth-1 prefetch of next chunk
            const int c = (ks + 1) * 8 + cbase;
            nw0 = Wrow[c];  nw1 = Wrow[c + 1];
            nb0v = Brow[c]; nb1v = Brow[c + 1];
        }
        uint wpk[4], bpk[4];
        {
            const float w0 = cw0.x, w1 = cw0.y, w2 = cw0.z, w3 = cw0.w;
            const float c0 = cb0.x, c1 = cb0.y, c2 = cb0.z, c3 = cb0.w;
            wn2 = fmaf(w0, w0, fmaf(w1, w1, fmaf(w2, w2, fmaf(w3, w3, wn2))));
            nb2 = fmaf(c0, c0, fmaf(c1, c1, fmaf(c2, c2, fmaf(c3, c3, nb2))));
            bw  = fmaf(c0, w0, fmaf(c1, w1, fmaf(c2, w2, fmaf(c3, w3, bw))));
            wpk[0] = pack2bf(w0, w1);  wpk[1] = pack2bf(w2, w3);
            bpk[0] = pack2bf(c0, c1);  bpk[1] = pack2bf(c2, c3);
        }
        {
            const float w0 = cw1.x, w1 = cw1.y, w2 = cw1.z, w3 = cw1.w;
            const float c0 = cb1.x, c1 = cb1.y, c2 = cb1.z, c3 = cb1.w;
            wn2 = fmaf(w0, w0, fmaf(w1, w1, fmaf(w2, w2, fmaf(w3, w3, wn2))));
            nb2 = fmaf(c0, c0, fmaf(c1, c1, fmaf(c2, c2, fmaf(c3, c3, nb2))));
            bw  = fmaf(c0, w0, fmaf(c1, w1, fmaf(c2, w2, fmaf(c3, w3, bw))));
            wpk[2] = pack2bf(w0, w1);  wpk[3] = pack2bf(w2, w3);
            bpk[2] = pack2bf(c0, c1);  bpk[3] = pack2bf(c2, c3);
        }
        wf[ks] = *(const short8x*)wpk;
        bf[ks] = *(const short8x*)bpk;
        if (ks < 3) { cw0 = nw0; cw1 = nw1; cb0 = nb0v; cb1 = nb1v; }
    }
    // reduce over the 4 q-groups: lanes {m16, m16+16, m16+32, m16+48} share u
    nb2 += __shfl_xor(nb2, 16);  bw += __shfl_xor(bw, 16);  wn2 += __shfl_xor(wn2, 16);
    nb2 += __shfl_xor(nb2, 32);  bw += __shfl_xor(bw, 32);  wn2 += __shfl_xor(wn2, 32);
    const float one_m  = 1.0f - nb2;
    const float a_norm = fabsf(one_m) * sqrtf(wn2);
    const float scale  = (2.0f / one_m) * a_norm;

    __syncthreads();

    // ---- A-fragments from LDS + MFMA
    const float4 nv4 = ((const float4*)nv2_lds)[q]; // rows q*4..q*4+3
    float4x accW = {0.f, 0.f, 0.f, 0.f};
    float4x accB = {0.f, 0.f, 0.f, 0.f};
    #pragma unroll
    for (int ks = 0; ks < 4; ++ks) {
        const short8x af = *(const short8x*)&XL[(ks * 64 + lane) * 4];
        accW = __builtin_amdgcn_mfma_f32_16x16x32_bf16(af, wf[ks], accW, 0, 0, 0);
        accB = __builtin_amdgcn_mfma_f32_16x16x32_bf16(af, bf[ks], accB, 0, 0, 0);
    }

    // ---- epilogue: C layout col = m16 (u), row = q*4+rg
    #pragma unroll
    for (int rg = 0; rg < 4; ++rg) {
        const float nv2  = ((const float*)&nv4)[rg];
        const float dot1 = accW[rg];
        const float xy   = -accB[rg];
        const float dd   = 1.0f + 2.0f * xy + nb2 * nv2;
        const float inv_dd = __builtin_amdgcn_rcpf(dd);
        const float alpha  = (1.0f + 2.0f * xy + nv2) * inv_dd;
        const float beta   = one_m * inv_dd;
        const float num = 2.0f * one_m * (beta * dot1 - alpha * bw);
        const float mm  = alpha * alpha * nb2 + 2.0f * alpha * beta * xy
                        + beta * beta * nv2;
        const float den = (1.0f - mm) * a_norm;
        const float z   = num * __builtin_amdgcn_rcpf(den);
        const float s   = sqrtf(fmaf(z, z, 1.0f));
        logits[q * 4 + rg][u] = scale * copysignf(__logf(fabsf(z) + s), z);
    }
    __syncthreads();

    // ---- softmax: wave w handles row w, float4 I/O
    {
        const float4 v = *(const float4*)&logits[wave][lane * 4];
        float mx = fmaxf(fmaxf(v.x, v.y), fmaxf(v.z, v.w));
        #pragma unroll
        for (int off = 32; off; off >>= 1) mx = fmaxf(mx, __shfl_xor(mx, off));
        float4 e;
        e.x = __expf(v.x - mx);  e.y = __expf(v.y - mx);
        e.z = __expf(v.z - mx);  e.w = __expf(v.w - mx);
        float s = e.x + e.y + e.z + e.w;
        #pragma unroll
        for (int off = 32; off; off >>= 1) s += __shfl_xor(s, off);
        const float inv = __builtin_amdgcn_rcpf(s);
        e.x *= inv;  e.y *= inv;  e.z *= inv;  e.w *= inv;
        ((float4*)(out + (size_t)(b0 + wave) * UN))[lane] = e;
    }
}

extern "C" void kernel_launch(void* const* d_in, const int* in_sizes, int n_in,
                              void* d_out, int out_size, void* d_ws, size_t ws_size,
                              hipStream_t stream) {
    const float* x    = (const float*)d_in[0];
    const float* W    = (const float*)d_in[1];
    const float* bias = (const float*)d_in[2];
    float* out = (float*)d_out;
    (void)d_ws; (void)ws_size;

    hipLaunchKernelGGL(fused_kernel, dim3(BN / MROW), dim3(BLOCK), 0, stream,
                       x, W, bias, out);
}

// Round 4
// 64.220 us; speedup vs baseline: 1.0605x; 1.0605x over previous
//
#include <hip/hip_runtime.h>
#include <hip/hip_bf16.h>
#include <math.h>

// Problem constants (B,U,D) = (4096, 256, 128)
#define BN 4096
#define UN 256
#define DN 128
#define MROW 16        // batch rows per block (one M=16 MFMA tile)
#define BLOCK 1024     // 16 waves: wave w owns u-tile w
#define LSTRIDE 260    // logits row stride; 260 % 32 == 4 -> 2-way banks (free)

typedef __attribute__((ext_vector_type(8))) short short8x;   // 8 bf16
typedef __attribute__((ext_vector_type(4))) float float4x;   // MFMA C/D

// d_ws layout (bytes):
//   Wp [0,      65536)  bf16 W,   fragment order: chunk = (u>>4)*256 + ks*64 + q*16 + (u&15)
//   Bp [65536, 131072)  bf16 bias, same order
//   S  [131072,135168)  float4[256] per-u: (nb2, bw, a_norm, scale) -- exact f32

__device__ inline uint pack2bf(float a, float b) {
    __hip_bfloat16 ha = __float2bfloat16(a);
    __hip_bfloat16 hb = __float2bfloat16(b);
    return (uint)(*(ushort*)&ha) | ((uint)(*(ushort*)&hb) << 16);
}

// ---- prep: W/bias -> bf16 fragment layout + per-u epilogue constants ----
// 16 blocks x 1024 threads: wave w of block b handles u = b*16 + w.
__global__ __launch_bounds__(1024) void prep_wb(
    const float* __restrict__ W, const float* __restrict__ bias,
    ushort* __restrict__ Wp, ushort* __restrict__ Bp, float4* __restrict__ S)
{
    const int u = blockIdx.x * 16 + (threadIdx.x >> 6);
    const int l = threadIdx.x & 63;       // 64 lanes, 2 floats each
    const float2 w2 = ((const float2*)(W    + (size_t)u * DN))[l];
    const float2 b2 = ((const float2*)(bias + (size_t)u * DN))[l];
    float nb2 = b2.x*b2.x + b2.y*b2.y;
    float bw  = b2.x*w2.x + b2.y*w2.y;
    float wn2 = w2.x*w2.x + w2.y*w2.y;
    #pragma unroll
    for (int off = 32; off; off >>= 1) {
        nb2 += __shfl_xor(nb2, off);
        bw  += __shfl_xor(bw , off);
        wn2 += __shfl_xor(wn2, off);
    }
    const int d  = 2 * l;
    const int ks = d >> 5, q = (d & 31) >> 3, j = d & 7;
    const int chunk = ((u >> 4) * 256) + ks * 64 + q * 16 + (u & 15);
    ((uint*)Wp)[chunk * 4 + (j >> 1)] = pack2bf(w2.x, w2.y);
    ((uint*)Bp)[chunk * 4 + (j >> 1)] = pack2bf(b2.x, b2.y);
    if (l == 0) {
        const float one_m  = 1.0f - nb2;
        const float a_norm = fabsf(one_m) * sqrtf(wn2);
        const float scale  = (2.0f / one_m) * a_norm;
        S[u] = make_float4(nb2, bw, a_norm, scale);
    }
}

// ---- main: in-kernel x staging + MFMA + epilogue + softmax ----
__global__ __launch_bounds__(BLOCK, 4) void main_kernel(
    const float* __restrict__ x,
    const ushort* __restrict__ Wp, const ushort* __restrict__ Bp,
    const float4* __restrict__ S, float* __restrict__ out)
{
    __shared__ __align__(16) uint XL[MROW * DN / 2];   // 4 KB, bf16 fragment order
    __shared__ float nv2_lds[MROW];
    __shared__ float logits[MROW][LSTRIDE];            // ~16.6 KB

    const int t    = threadIdx.x;
    const int lane = t & 63;
    const int wave = t >> 6;          // u-tile index; also x-row during staging
    const int m16  = lane & 15;
    const int q    = lane >> 4;
    const int b0   = blockIdx.x * MROW;
    const int u    = wave * 16 + m16;

    // ---- issue W/bias/S global loads FIRST (no LDS dependency) so their
    //      latency overlaps the x staging phase below.
    const short8x* wc = (const short8x*)Wp + wave * 256 + lane;
    const short8x* bc = (const short8x*)Bp + wave * 256 + lane;
    short8x wf[4], bf[4];
    #pragma unroll
    for (int ks = 0; ks < 4; ++ks) {
        wf[ks] = wc[ks * 64];
        bf[ks] = bc[ks * 64];
    }
    const float4 sc = S[u];                         // per-u epilogue constants

    // ---- phase A: stage x tile. wave w loads row w (64 lanes x float2,
    //      512B contiguous per wave), packs bf16 into fragment-order LDS.
    {
        const int d0 = lane * 2;
        const float2 v = *(const float2*)(x + (size_t)(b0 + wave) * DN + d0);
        float sq = fmaf(v.x, v.x, v.y * v.y);
        #pragma unroll
        for (int off = 32; off; off >>= 1) sq += __shfl_xor(sq, off);
        if (lane == 0) nv2_lds[wave] = sq;          // exact f32 ||x_row||^2
        const int ks = d0 >> 5, qq = (d0 & 31) >> 3, j = d0 & 7;
        XL[(ks * 64 + qq * 16 + wave) * 4 + (j >> 1)] = pack2bf(v.x, v.y);
    }

    __syncthreads();

    // ---- A-fragments from LDS + MFMA
    const float4 nv4 = ((const float4*)nv2_lds)[q]; // rows q*4..q*4+3
    float4x accW = {0.f, 0.f, 0.f, 0.f};
    float4x accB = {0.f, 0.f, 0.f, 0.f};
    #pragma unroll
    for (int ks = 0; ks < 4; ++ks) {
        const short8x af = *(const short8x*)&XL[(ks * 64 + lane) * 4];
        accW = __builtin_amdgcn_mfma_f32_16x16x32_bf16(af, wf[ks], accW, 0, 0, 0);
        accB = __builtin_amdgcn_mfma_f32_16x16x32_bf16(af, bf[ks], accB, 0, 0, 0);
    }

    // ---- epilogue: C layout col = m16 (u), row = q*4+rg
    const float nb2 = sc.x, bw = sc.y, a_norm = sc.z, scale = sc.w;
    const float one_m = 1.0f - nb2;
    #pragma unroll
    for (int rg = 0; rg < 4; ++rg) {
        const float nv2  = ((const float*)&nv4)[rg];
        const float dot1 = accW[rg];
        const float xy   = -accB[rg];
        const float dd   = 1.0f + 2.0f * xy + nb2 * nv2;
        const float inv_dd = __builtin_amdgcn_rcpf(dd);
        const float alpha  = (1.0f + 2.0f * xy + nv2) * inv_dd;
        const float beta   = one_m * inv_dd;
        const float num = 2.0f * one_m * (beta * dot1 - alpha * bw);
        const float mm  = alpha * alpha * nb2 + 2.0f * alpha * beta * xy
                        + beta * beta * nv2;
        const float den = (1.0f - mm) * a_norm;
        const float z   = num * __builtin_amdgcn_rcpf(den);
        const float s   = sqrtf(fmaf(z, z, 1.0f));
        logits[q * 4 + rg][u] = scale * copysignf(__logf(fabsf(z) + s), z);
    }
    __syncthreads();

    // ---- softmax: wave w handles row w, float4 I/O
    {
        const float4 v = *(const float4*)&logits[wave][lane * 4];
        float mx = fmaxf(fmaxf(v.x, v.y), fmaxf(v.z, v.w));
        #pragma unroll
        for (int off = 32; off; off >>= 1) mx = fmaxf(mx, __shfl_xor(mx, off));
        float4 e;
        e.x = __expf(v.x - mx);  e.y = __expf(v.y - mx);
        e.z = __expf(v.z - mx);  e.w = __expf(v.w - mx);
        float s = e.x + e.y + e.z + e.w;
        #pragma unroll
        for (int off = 32; off; off >>= 1) s += __shfl_xor(s, off);
        const float inv = __builtin_amdgcn_rcpf(s);
        e.x *= inv;  e.y *= inv;  e.z *= inv;  e.w *= inv;
        ((float4*)(out + (size_t)(b0 + wave) * UN))[lane] = e;
    }
}

extern "C" void kernel_launch(void* const* d_in, const int* in_sizes, int n_in,
                              void* d_out, int out_size, void* d_ws, size_t ws_size,
                              hipStream_t stream) {
    const float* x    = (const float*)d_in[0];
    const float* W    = (const float*)d_in[1];
    const float* bias = (const float*)d_in[2];
    float* out = (float*)d_out;

    char* ws = (char*)d_ws;
    ushort* Wp = (ushort*)(ws);
    ushort* Bp = (ushort*)(ws + 65536);
    float4* S  = (float4*)(ws + 131072);

    hipLaunchKernelGGL(prep_wb, dim3(UN / 16), dim3(1024), 0, stream, W, bias, Wp, Bp, S);
    hipLaunchKernelGGL(main_kernel, dim3(BN / MROW), dim3(BLOCK), 0, stream,
                       x, Wp, Bp, S, out);
}